// Round 4
// baseline (768.234 us; speedup 1.0000x reference)
//
#include <hip/hip_runtime.h>
#include <hip/hip_bf16.h>

// Problem constants (BasicRecurrentLayer): B=64, T=1024, F=128, U=256
constexpr int B = 64;
constexpr int T = 1024;
constexpr int F = 128;
constexpr int U = 256;
constexpr int CH = 8;       // rnn: steps per h-prefetch/out-flush chunk

typedef float f2 __attribute__((ext_vector_type(2)));

// ---------------------------------------------------------------------------
// h storage helpers (fp32 if workspace fits 64 MB, else bf16 = 32 MB)
// ---------------------------------------------------------------------------
__device__ __forceinline__ float toF32(float v) { return v; }
__device__ __forceinline__ float toF32(__hip_bfloat16 v) { return __bfloat162float(v); }

__device__ __forceinline__ void store8(float* p, const float* a) {
    ((float4*)p)[0] = make_float4(a[0], a[1], a[2], a[3]);
    ((float4*)p)[1] = make_float4(a[4], a[5], a[6], a[7]);
}
__device__ __forceinline__ void store8(__hip_bfloat16* p, const float* a) {
    unsigned int v[4];
    #pragma unroll
    for (int i = 0; i < 4; ++i) {
        __hip_bfloat16 lo = __float2bfloat16(a[2 * i]);
        __hip_bfloat16 hi = __float2bfloat16(a[2 * i + 1]);
        unsigned short lob = *(unsigned short*)&lo;
        unsigned short hib = *(unsigned short*)&hi;
        v[i] = (unsigned int)lob | ((unsigned int)hib << 16);
    }
    ((uint4*)p)[0] = make_uint4(v[0], v[1], v[2], v[3]);
}

__device__ __forceinline__ float rdlane(unsigned int v, int l) {
    return __uint_as_float(__builtin_amdgcn_readlane(v, l));
}

// Exact identity tanh(x) = 1 - 2/(1+e^{2x}); e^{2x} = exp2(x*2*log2(e)).
__device__ __forceinline__ float tanh_fast(float x) {
    float e = __builtin_amdgcn_exp2f(x * 2.885390081777927f);
    float r = __builtin_amdgcn_rcpf(1.0f + e);
    return fmaf(-2.0f, r, 1.0f);
}

// lgkmcnt(0) only (vmcnt=63, expcnt=7 -> no wait): 0xC07F. Raw barrier that
// does NOT drain vmcnt, so h-prefetch / out-stores stay in flight across it.
__device__ __forceinline__ void lds_barrier() {
    __builtin_amdgcn_s_waitcnt(0xC07F);
    asm volatile("" ::: "memory");
    __builtin_amdgcn_s_barrier();
    asm volatile("" ::: "memory");
}

// ---------------------------------------------------------------------------
// Kernel 1: projection  h[t, b, u] = sum_f inputs[b, t, f] * R[f, u]
// (unchanged from round 3 — works; rnn dominates runtime)
// ---------------------------------------------------------------------------
template <typename HT>
__global__ __launch_bounds__(512, 2) void proj_kernel(
    const float* __restrict__ in,   // [B, T, F]
    const float* __restrict__ Rm,   // [F, U]
    HT* __restrict__ h)             // [T, B, U]
{
    const int t0   = blockIdx.x * 64;
    const int u0b  = blockIdx.y * 64;
    const int b    = blockIdx.z;
    const int tid  = threadIdx.x;
    const int lane = tid & 63;      // = r (t-row within tile)
    const int wv   = tid >> 6;      // 0..7
    const int u0   = __builtin_amdgcn_readfirstlane(u0b + wv * 8);

    __shared__ float4 a4[64 * 32];  // 32 KB, swizzled

    const float4* src = (const float4*)(in + ((size_t)b * T + t0) * F);
    #pragma unroll
    for (int it = 0; it < 4; ++it) {
        int f  = tid + it * 512;        // 0..2047 coalesced
        int r  = f >> 5;
        int k4 = f & 31;
        a4[(r << 5) | (k4 ^ (r & 31))] = src[f];
    }
    __syncthreads();

    const float* Rp = Rm + u0;      // wave-uniform -> scalar loads
    float acc[8];
    #pragma unroll
    for (int j = 0; j < 8; ++j) acc[j] = 0.f;

    float ra[32], rb[32];           // uniform (SGPR) ping-pong R buffers
    #pragma unroll
    for (int kk = 0; kk < 4; ++kk)
        #pragma unroll
        for (int j = 0; j < 8; ++j)
            ra[kk * 8 + j] = Rp[(size_t)kk * U + j];

    const int r = lane;
    #pragma unroll
    for (int k4 = 0; k4 < 32; k4 += 2) {
        #pragma unroll
        for (int kk = 0; kk < 4; ++kk)
            #pragma unroll
            for (int j = 0; j < 8; ++j)
                rb[kk * 8 + j] = Rp[(size_t)((k4 + 1) * 4 + kk) * U + j];

        float4 av = a4[(r << 5) | (k4 ^ (r & 31))];
        #pragma unroll
        for (int j = 0; j < 8; ++j) {
            acc[j] = fmaf(av.x, ra[0 * 8 + j], acc[j]);
            acc[j] = fmaf(av.y, ra[1 * 8 + j], acc[j]);
            acc[j] = fmaf(av.z, ra[2 * 8 + j], acc[j]);
            acc[j] = fmaf(av.w, ra[3 * 8 + j], acc[j]);
        }

        if (k4 + 2 < 32) {
            #pragma unroll
            for (int kk = 0; kk < 4; ++kk)
                #pragma unroll
                for (int j = 0; j < 8; ++j)
                    ra[kk * 8 + j] = Rp[(size_t)((k4 + 2) * 4 + kk) * U + j];
        }

        float4 av2 = a4[(r << 5) | ((k4 + 1) ^ (r & 31))];
        #pragma unroll
        for (int j = 0; j < 8; ++j) {
            acc[j] = fmaf(av2.x, rb[0 * 8 + j], acc[j]);
            acc[j] = fmaf(av2.y, rb[1 * 8 + j], acc[j]);
            acc[j] = fmaf(av2.z, rb[2 * 8 + j], acc[j]);
            acc[j] = fmaf(av2.w, rb[3 * 8 + j], acc[j]);
        }
    }

    HT* hp = h + ((size_t)(t0 + r) * B + b) * U + u0;
    store8(hp, acc);
}

// ---------------------------------------------------------------------------
// Kernel 2: recurrence. Grid 64 (one WG per batch row), 512 threads = 8 waves.
// Wave wv owns k-range [32wv, 32wv+32) for the GEMV and reduces u'-range
// [32wv, 32wv+32).  Lane l covers u-columns {2l, 2l+1} (lower half) and
// {128+2l, 128+2l+1} (upper half), with W stored as k-PAIR float2 fragments:
//   wA0[kk] = {W[k0+2kk][2l], W[k0+2kk+1][2l]}  etc. (128 VGPRs total)
// Per step per wave: 32 v_readlane (state k-pair broadcast) + 64 v_pk_fma_f32
// (via __builtin_elementwise_fma on float2 -> V_PK_FMA_F32) + 2 ds_write_b64
// + ONE lgkm-only barrier + 8 ds_read_b32 reduce + tanh. The reduced value tv
// sits in this wave's own lanes — it IS next step's readlane source (no state
// write-back, no second barrier). Partials double-buffered by step parity.
// ---------------------------------------------------------------------------
template <typename HT>
__global__ __launch_bounds__(512, 2) void rnn_kernel(
    const HT* __restrict__ h,        // [T, B, U]
    const float* __restrict__ Wm,    // [U, U]
    const float* __restrict__ bias,  // [U]
    const float* __restrict__ x0,    // [U]
    float* __restrict__ out)         // [T, B, U]
{
    const int b    = blockIdx.x;
    const int tid  = threadIdx.x;
    const int l    = tid & 63;
    const int wv   = tid >> 6;       // 0..7
    const int k0   = wv << 5;        // wave's k-range base
    const int up   = k0 + (l & 31);  // u' this lane reduces / holds in tv
    const int half = wv >> 2;        // 0: u' in [0,128), 1: [128,256)
    const int uin  = up & 127;

    __shared__ float p[2][2][8][128];   // [parity][u-half][wave][u-in-half]

    // W fragments as k-pairs (float2), 128 VGPRs total.
    f2 wA0[16], wA1[16], wB0[16], wB1[16];
    {
        const float* base = Wm + (size_t)k0 * U + 2 * l;
        #pragma unroll
        for (int kk = 0; kk < 16; ++kk) {
            const float* r0 = base + (size_t)(2 * kk) * U;
            const float* r1 = r0 + U;
            f2 a0 = *(const f2*)(r0);        // {W[2kk][2l],   W[2kk][2l+1]}
            f2 a1 = *(const f2*)(r1);        // {W[2kk+1][2l], W[2kk+1][2l+1]}
            wA0[kk] = (f2){a0.x, a1.x};
            wA1[kk] = (f2){a0.y, a1.y};
            f2 b0 = *(const f2*)(r0 + 128);
            f2 b1 = *(const f2*)(r1 + 128);
            wB0[kk] = (f2){b0.x, b1.x};
            wB1[kk] = (f2){b0.y, b1.y};
        }
    }

    const bool act = (l < 32);
    const float bv = bias[up];
    float tv = x0[up];               // s[up]; lanes 32..63 duplicate 0..31

    const size_t sT = (size_t)B * U;
    const HT* hp = h + (size_t)b * U + up;
    float* op = out + (size_t)b * U + up;

    float hc[CH], hn[CH], ob[CH];
    #pragma unroll
    for (int i = 0; i < CH; ++i) hc[i] = toF32(hp[(size_t)i * sT]);

    for (int tc = 0; tc < T; tc += CH) {
        // prefetch next chunk's h (floats across lgkm-only barriers)
        if (tc + CH < T) {
            #pragma unroll
            for (int i = 0; i < CH; ++i)
                hn[i] = toF32(hp[(size_t)(tc + CH + i) * sT]);
        }
        // flush previous chunk's outputs
        if (tc > 0 && act) {
            #pragma unroll
            for (int i = 0; i < CH; ++i)
                op[(size_t)(tc - CH + i) * sT] = ob[i];
        }

        #pragma unroll
        for (int i = 0; i < CH; ++i) {
            const unsigned int tvu = __float_as_uint(tv);
            f2 aA0 = {0.f, 0.f}, aA1 = {0.f, 0.f};
            f2 aB0 = {0.f, 0.f}, aB1 = {0.f, 0.f};
            #pragma unroll
            for (int kk = 0; kk < 16; ++kk) {
                f2 sp = { rdlane(tvu, 2 * kk), rdlane(tvu, 2 * kk + 1) };
                aA0 = __builtin_elementwise_fma(wA0[kk], sp, aA0);
                aA1 = __builtin_elementwise_fma(wA1[kk], sp, aA1);
                aB0 = __builtin_elementwise_fma(wB0[kk], sp, aB0);
                aB1 = __builtin_elementwise_fma(wB1[kk], sp, aB1);
            }
            const int par = i & 1;
            *(f2*)&p[par][0][wv][2 * l] = (f2){aA0.x + aA0.y, aA1.x + aA1.y};
            *(f2*)&p[par][1][wv][2 * l] = (f2){aB0.x + aB0.y, aB1.x + aB1.y};

            lds_barrier();           // ONE barrier per step (lgkm only)

            // reduce 8 wave-partials for u' (lanes 32..63 duplicate: free
            // same-address broadcast)
            const float* pr = &p[par][half][0][uin];
            float red = pr[0];
            #pragma unroll
            for (int w2 = 1; w2 < 8; ++w2) red += pr[w2 * 128];

            float val = tanh_fast(red + hc[i] + bv);
            ob[i] = val;
            tv = val;                // next step's readlane source
        }

        if (tc + CH < T) {
            #pragma unroll
            for (int i = 0; i < CH; ++i) hc[i] = hn[i];
        }
    }

    if (act) {
        #pragma unroll
        for (int i = 0; i < CH; ++i)
            op[(size_t)(T - CH + i) * sT] = ob[i];
    }
}

// ---------------------------------------------------------------------------
extern "C" void kernel_launch(void* const* d_in, const int* in_sizes, int n_in,
                              void* d_out, int out_size, void* d_ws, size_t ws_size,
                              hipStream_t stream) {
    const float* in   = (const float*)d_in[0];  // [B, T, F]
    const float* Rm   = (const float*)d_in[1];  // [F, U]
    const float* Wm   = (const float*)d_in[2];  // [U, U]
    const float* bias = (const float*)d_in[3];  // [U]
    const float* x0   = (const float*)d_in[4];  // [U]
    float* out = (float*)d_out;                 // [T, B, U]

    const size_t hElems = (size_t)T * B * U;
    dim3 pgrid(T / 64, U / 64, B);

    if (ws_size >= hElems * sizeof(float)) {
        float* h = (float*)d_ws;
        proj_kernel<float><<<pgrid, 512, 0, stream>>>(in, Rm, h);
        rnn_kernel<float><<<dim3(B), 512, 0, stream>>>(h, Wm, bias, x0, out);
    } else {
        __hip_bfloat16* h = (__hip_bfloat16*)d_ws;
        proj_kernel<__hip_bfloat16><<<pgrid, 512, 0, stream>>>(in, Rm, h);
        rnn_kernel<__hip_bfloat16><<<dim3(B), 512, 0, stream>>>(h, Wm, bias, x0, out);
    }
}

// Round 6
// 684.248 us; speedup vs baseline: 1.1227x; 1.1227x over previous
//
#include <hip/hip_runtime.h>
#include <hip/hip_bf16.h>

// Problem constants (BasicRecurrentLayer): B=64, T=1024, F=128, U=256
constexpr int B = 64;
constexpr int T = 1024;
constexpr int F = 128;
constexpr int U = 256;
constexpr int CH = 4;       // rnn: steps per h-prefetch/out-flush chunk

typedef _Float16 h2 __attribute__((ext_vector_type(2)));

// ---------------------------------------------------------------------------
// helpers
// ---------------------------------------------------------------------------
__device__ __forceinline__ void store8(float* p, const float* a) {
    ((float4*)p)[0] = make_float4(a[0], a[1], a[2], a[3]);
    ((float4*)p)[1] = make_float4(a[4], a[5], a[6], a[7]);
}
__device__ __forceinline__ void store8(__hip_bfloat16* p, const float* a) {
    unsigned int v[4];
    #pragma unroll
    for (int i = 0; i < 4; ++i) {
        __hip_bfloat16 lo = __float2bfloat16(a[2 * i]);
        __hip_bfloat16 hi = __float2bfloat16(a[2 * i + 1]);
        unsigned short lob = *(unsigned short*)&lo;
        unsigned short hib = *(unsigned short*)&hi;
        v[i] = (unsigned int)lob | ((unsigned int)hib << 16);
    }
    ((uint4*)p)[0] = make_uint4(v[0], v[1], v[2], v[3]);
}

// raw h-chunk types: bf16 h -> ushort4 (8B), fp32 h -> float4 (16B)
template <typename HT> struct HRawT;
template <> struct HRawT<float>           { using T = float4;  };
template <> struct HRawT<__hip_bfloat16>  { using T = ushort4; };

__device__ __forceinline__ float4 toF4(float4 v) { return v; }
__device__ __forceinline__ float4 toF4(ushort4 v) {
    float4 r;
    r.x = __uint_as_float((unsigned)v.x << 16);
    r.y = __uint_as_float((unsigned)v.y << 16);
    r.z = __uint_as_float((unsigned)v.z << 16);
    r.w = __uint_as_float((unsigned)v.w << 16);
    return r;
}

// pack 2 f32 -> half2 with round-to-nearest (v_cvt_f16_f32 x2 + v_pack_b32_f16)
__device__ __forceinline__ unsigned pack_rn(float a, float b) {
    h2 p = { (_Float16)a, (_Float16)b };
    return __builtin_bit_cast(unsigned, p);
}

// Exact identity tanh(x) = 1 - 2/(1+e^{2x}); e^{2x} = exp2(x*2*log2(e)).
__device__ __forceinline__ float tanh_fast(float x) {
    float e = __builtin_amdgcn_exp2f(x * 2.885390081777927f);
    float r = __builtin_amdgcn_rcpf(1.0f + e);
    return fmaf(-2.0f, r, 1.0f);
}

// lgkmcnt(0)-only barrier (vmcnt=63, expcnt=7 -> not waited): prefetched
// global loads / output stores stay in flight across it.
__device__ __forceinline__ void lds_barrier() {
    __builtin_amdgcn_s_waitcnt(0xC07F);
    asm volatile("" ::: "memory");
    __builtin_amdgcn_s_barrier();
    asm volatile("" ::: "memory");
}

// one DPP reduce round: x += lane(x shifted by CTRL within row-16), OOB=0.
// CTRL must be an immediate -> template parameter.
template <int CTRL>
__device__ __forceinline__ float dpp_add(float x) {
    int sh = __builtin_amdgcn_update_dpp(0, __float_as_int(x), CTRL, 0xF, 0xF, true);
    return x + __int_as_float(sh);
}

// ---------------------------------------------------------------------------
// Kernel 1: projection  h[t, b, u] = sum_f inputs[b, t, f] * R[f, u]
// (unchanged from round 3 — rnn dominates runtime)
// ---------------------------------------------------------------------------
template <typename HT>
__global__ __launch_bounds__(512, 2) void proj_kernel(
    const float* __restrict__ in,   // [B, T, F]
    const float* __restrict__ Rm,   // [F, U]
    HT* __restrict__ h)             // [T, B, U]
{
    const int t0   = blockIdx.x * 64;
    const int u0b  = blockIdx.y * 64;
    const int b    = blockIdx.z;
    const int tid  = threadIdx.x;
    const int lane = tid & 63;      // = r (t-row within tile)
    const int wv   = tid >> 6;      // 0..7
    const int u0   = __builtin_amdgcn_readfirstlane(u0b + wv * 8);

    __shared__ float4 a4[64 * 32];  // 32 KB, swizzled

    const float4* src = (const float4*)(in + ((size_t)b * T + t0) * F);
    #pragma unroll
    for (int it = 0; it < 4; ++it) {
        int f  = tid + it * 512;        // 0..2047 coalesced
        int r  = f >> 5;
        int k4 = f & 31;
        a4[(r << 5) | (k4 ^ (r & 31))] = src[f];
    }
    __syncthreads();

    const float* Rp = Rm + u0;      // wave-uniform -> scalar loads
    float acc[8];
    #pragma unroll
    for (int j = 0; j < 8; ++j) acc[j] = 0.f;

    float ra[32], rb[32];           // uniform (SGPR) ping-pong R buffers
    #pragma unroll
    for (int kk = 0; kk < 4; ++kk)
        #pragma unroll
        for (int j = 0; j < 8; ++j)
            ra[kk * 8 + j] = Rp[(size_t)kk * U + j];

    const int r = lane;
    #pragma unroll
    for (int k4 = 0; k4 < 32; k4 += 2) {
        #pragma unroll
        for (int kk = 0; kk < 4; ++kk)
            #pragma unroll
            for (int j = 0; j < 8; ++j)
                rb[kk * 8 + j] = Rp[(size_t)((k4 + 1) * 4 + kk) * U + j];

        float4 av = a4[(r << 5) | (k4 ^ (r & 31))];
        #pragma unroll
        for (int j = 0; j < 8; ++j) {
            acc[j] = fmaf(av.x, ra[0 * 8 + j], acc[j]);
            acc[j] = fmaf(av.y, ra[1 * 8 + j], acc[j]);
            acc[j] = fmaf(av.z, ra[2 * 8 + j], acc[j]);
            acc[j] = fmaf(av.w, ra[3 * 8 + j], acc[j]);
        }

        if (k4 + 2 < 32) {
            #pragma unroll
            for (int kk = 0; kk < 4; ++kk)
                #pragma unroll
                for (int j = 0; j < 8; ++j)
                    ra[kk * 8 + j] = Rp[(size_t)((k4 + 2) * 4 + kk) * U + j];
        }

        float4 av2 = a4[(r << 5) | ((k4 + 1) ^ (r & 31))];
        #pragma unroll
        for (int j = 0; j < 8; ++j) {
            acc[j] = fmaf(av2.x, rb[0 * 8 + j], acc[j]);
            acc[j] = fmaf(av2.y, rb[1 * 8 + j], acc[j]);
            acc[j] = fmaf(av2.z, rb[2 * 8 + j], acc[j]);
            acc[j] = fmaf(av2.w, rb[3 * 8 + j], acc[j]);
        }
    }

    HT* hp = h + ((size_t)(t0 + r) * B + b) * U + u0;
    store8(hp, acc);
}

// ---------------------------------------------------------------------------
// Kernel 2: recurrence. Grid 64 (one WG per batch row), 256 threads = 4 waves.
// Wave wv owns k-range [64wv, 64wv+64) AND reduces u-range [64wv, 64wv+64).
// Lane l covers u-columns {4l..4l+3}; W stored as packed f16 k-pairs:
//   wp{j}[kk] = half2{ W[k0+2kk][4l+j], W[k0+2kk+1][4l+j] }   (64 VGPRs)
// Per step per wave:
//   32 v_readlane (packed state k-pairs -> SGPRs)
//   128 v_dot2_f32_f16 (8 acc chains), 1 ds_write_b128 (partials, padded)
//   ONE lgkm-only barrier
//   1 ds_read_b128 (all 4 waves' partials for this lane's u-quad)
//   DPP reduce over 4-lane groups (2 rounds, owner = lane 4q+3)
//   + h + bias, 4x tanh, RN-pack to 2 half2 (next step's readlane source)
// Partials double-buffered by step parity; no state write-back needed.
// ---------------------------------------------------------------------------
template <typename HT>
__global__ __launch_bounds__(256, 1) void rnn_kernel(
    const HT* __restrict__ h,        // [T, B, U]
    const float* __restrict__ Wm,    // [U, U]
    const float* __restrict__ bias,  // [U]
    const float* __restrict__ x0,    // [U]
    float* __restrict__ out)         // [T, B, U]
{
    using Raw = typename HRawT<HT>::T;

    const int b   = blockIdx.x;
    const int tid = threadIdx.x;
    const int l   = tid & 63;
    const int wv  = tid >> 6;        // 0..3
    const int k0  = wv << 6;         // k-range base, also u-reduce base
    const int q   = l >> 2;          // u-quad within this wave's range (0..15)
    const int w2  = l & 3;           // which wave's partial this lane reduces
    const int ub  = k0 + 4 * q;      // u-quad base for reduce/h/out
    const bool owner = (w2 == 3);

    __shared__ float pp[2][4 * 264]; // padded (264) partials, double-buffered

    // ---- W fragments (one-time, RN rounding) ----
    h2 wp0[32], wp1[32], wp2[32], wp3[32];
    {
        const float* wb = Wm + (size_t)k0 * U + 4 * l;
        #pragma unroll
        for (int kk = 0; kk < 32; ++kk) {
            float4 r0 = *(const float4*)(wb + (size_t)(2 * kk) * U);
            float4 r1 = *(const float4*)(wb + (size_t)(2 * kk + 1) * U);
            wp0[kk] = h2{ (_Float16)r0.x, (_Float16)r1.x };
            wp1[kk] = h2{ (_Float16)r0.y, (_Float16)r1.y };
            wp2[kk] = h2{ (_Float16)r0.z, (_Float16)r1.z };
            wp3[kk] = h2{ (_Float16)r0.w, (_Float16)r1.w };
        }
    }

    // ---- initial packed state (all lanes in a 4-group hold the same quad) ----
    float4 sv = *(const float4*)(x0 + ub);
    unsigned spA = pack_rn(sv.x, sv.y);   // pair 2q   (valid in owner lanes)
    unsigned spB = pack_rn(sv.z, sv.w);   // pair 2q+1

    const float4 bv = *(const float4*)(bias + ub);

    const size_t sT = (size_t)B * U;
    const HT* hp = h + (size_t)b * U + ub;
    float* op = out + (size_t)b * U + ub;

    Raw hcr[CH], hnr[CH];
    float4 ob[CH];
    #pragma unroll
    for (int i = 0; i < CH; ++i)
        hcr[i] = *(const Raw*)(hp + (size_t)i * sT);

    for (int tc = 0; tc < T; tc += CH) {
        if (tc + CH < T) {
            #pragma unroll
            for (int i = 0; i < CH; ++i)
                hnr[i] = *(const Raw*)(hp + (size_t)(tc + CH + i) * sT);
        }
        if (tc > 0 && owner) {
            #pragma unroll
            for (int i = 0; i < CH; ++i)
                *(float4*)(op + (size_t)(tc - CH + i) * sT) = ob[i];
        }

        #pragma unroll
        for (int i = 0; i < CH; ++i) {
            // ---- broadcast: 32 packed k-pairs -> SGPRs (owner lanes 4q'+3) ----
            unsigned sb[32];
            #pragma unroll
            for (int kk = 0; kk < 32; ++kk)
                sb[kk] = __builtin_amdgcn_readlane((kk & 1) ? spB : spA,
                                                   4 * (kk >> 1) + 3);

            // ---- GEMV partial: 128 dot2, 8 accumulator chains ----
            float a0 = 0.f, a1 = 0.f, a2 = 0.f, a3 = 0.f;
            float a4 = 0.f, a5 = 0.f, a6 = 0.f, a7 = 0.f;
            #pragma unroll
            for (int kk = 0; kk < 32; kk += 2) {
                h2 s0 = __builtin_bit_cast(h2, sb[kk]);
                h2 s1 = __builtin_bit_cast(h2, sb[kk + 1]);
                a0 = __builtin_amdgcn_fdot2(wp0[kk], s0, a0, false);
                a1 = __builtin_amdgcn_fdot2(wp1[kk], s0, a1, false);
                a2 = __builtin_amdgcn_fdot2(wp2[kk], s0, a2, false);
                a3 = __builtin_amdgcn_fdot2(wp3[kk], s0, a3, false);
                a4 = __builtin_amdgcn_fdot2(wp0[kk + 1], s1, a4, false);
                a5 = __builtin_amdgcn_fdot2(wp1[kk + 1], s1, a5, false);
                a6 = __builtin_amdgcn_fdot2(wp2[kk + 1], s1, a6, false);
                a7 = __builtin_amdgcn_fdot2(wp3[kk + 1], s1, a7, false);
            }

            const int par = i & 1;
            *(float4*)&pp[par][wv * 264 + 4 * l] =
                make_float4(a0 + a4, a1 + a5, a2 + a6, a3 + a7);

            lds_barrier();          // ONE barrier per step (lgkm only)

            // ---- read all 4 waves' partials for this lane's u-quad ----
            float4 rp = *(const float4*)&pp[par][w2 * 264 + ub];

            // ---- DPP reduce over the 4-lane group (sum over w2) ----
            rp.x = dpp_add<0x112>(dpp_add<0x111>(rp.x));
            rp.y = dpp_add<0x112>(dpp_add<0x111>(rp.y));
            rp.z = dpp_add<0x112>(dpp_add<0x111>(rp.z));
            rp.w = dpp_add<0x112>(dpp_add<0x111>(rp.w));

            // ---- h + bias + tanh (owner lanes have valid sums) ----
            float4 hv = toF4(hcr[i]);
            float4 val;
            val.x = tanh_fast(rp.x + hv.x + bv.x);
            val.y = tanh_fast(rp.y + hv.y + bv.y);
            val.z = tanh_fast(rp.z + hv.z + bv.z);
            val.w = tanh_fast(rp.w + hv.w + bv.w);
            ob[i] = val;

            // ---- pack next step's broadcast source (RN) ----
            spA = pack_rn(val.x, val.y);
            spB = pack_rn(val.z, val.w);
        }

        if (tc + CH < T) {
            #pragma unroll
            for (int i = 0; i < CH; ++i) hcr[i] = hnr[i];
        }
    }

    if (owner) {
        #pragma unroll
        for (int i = 0; i < CH; ++i)
            *(float4*)(op + (size_t)(T - CH + i) * sT) = ob[i];
    }
}

// ---------------------------------------------------------------------------
extern "C" void kernel_launch(void* const* d_in, const int* in_sizes, int n_in,
                              void* d_out, int out_size, void* d_ws, size_t ws_size,
                              hipStream_t stream) {
    const float* in   = (const float*)d_in[0];  // [B, T, F]
    const float* Rm   = (const float*)d_in[1];  // [F, U]
    const float* Wm   = (const float*)d_in[2];  // [U, U]
    const float* bias = (const float*)d_in[3];  // [U]
    const float* x0   = (const float*)d_in[4];  // [U]
    float* out = (float*)d_out;                 // [T, B, U]

    const size_t hElems = (size_t)T * B * U;
    dim3 pgrid(T / 64, U / 64, B);

    if (ws_size >= hElems * sizeof(float)) {
        float* h = (float*)d_ws;
        proj_kernel<float><<<pgrid, 512, 0, stream>>>(in, Rm, h);
        rnn_kernel<float><<<dim3(B), 256, 0, stream>>>(h, Wm, bias, x0, out);
    } else {
        __hip_bfloat16* h = (__hip_bfloat16*)d_ws;
        proj_kernel<__hip_bfloat16><<<pgrid, 512, 0, stream>>>(in, Rm, h);
        rnn_kernel<__hip_bfloat16><<<dim3(B), 256, 0, stream>>>(h, Wm, bias, x0, out);
    }
}